// Round 10
// baseline (338.711 us; speedup 1.0000x reference)
//
#include <hip/hip_runtime.h>
#include <math.h>

#define H_ 128
#define W_ 128
#define C_ 64
#define O_ 64
#define B_ 8
#define K2_ 9
#define HWSZ (H_*W_)

// vector global loads with only 4-byte alignment guarantee.
typedef float f2u __attribute__((ext_vector_type(2), aligned(4)));
typedef float f4u __attribute__((ext_vector_type(4), aligned(4)));

// ---------------------------------------------------------------------------
// Kernel P: weight prep.
//  wt  (K2, C, O)  : sample-GEMM weights, contiguous in o -> clean s_load.
//  wom (C, 28, 9)  : offset(18)+mask(9) conv weights per channel, row 27 = 0
//                    (pad so 4 output-quarters run fixed 7-row loops).
// ---------------------------------------------------------------------------
__global__ __launch_bounds__(256) void prep_weights_k(
    const float* __restrict__ w, const float* __restrict__ w_off,
    const float* __restrict__ w_mod, float* __restrict__ wt,
    float* __restrict__ wom) {
    int id = blockIdx.x * 256 + threadIdx.x;
    if (id < K2_ * C_ * O_) {              // id = k*C*O + c*O + o
        int o = id & (O_ - 1);
        int c = (id >> 6) & (C_ - 1);
        int k = id / (C_ * O_);
        wt[id] = w[(o * C_ + c) * K2_ + k];
    }
    int id2 = id - K2_ * C_ * O_;
    if (id2 >= 0 && id2 < C_ * 252) {      // id2 = c*252 + tt*9 + k
        int k = id2 % 9;
        int tt = (id2 / 9) % 28;
        int c = id2 / 252;
        float v = 0.0f;
        if (tt < 18)      v = w_off[(tt * C_ + c) * K2_ + k];
        else if (tt < 27) v = w_mod[((tt - 18) * C_ + c) * K2_ + k];
        wom[id2] = v;
    }
}

// ---------------------------------------------------------------------------
// Kernel A5: offset/mask 3x3 conv, occupancy-first.
// r8 (weight amortization) and r9 (TA-instruction count) both moved A <10%
// -- remaining hypothesis is latency-hiding starvation at 16 waves/CU with
// two dependent waits per c-iter (weight s_load block + tap vectors).
// A5: 1-row strips -> grid 1024 = 4 blocks/CU = 32 waves/CU (2x TLP);
// block = 128 cols x 4 o-quarters; thread = 1 pixel, full 64-c loop.
// Per c: three dwordx4 row loads (lanes stride 4B -> ~5 lines/instr),
// 9 taps via compile-time cndmask chains, 63 FMAs.
// Register budget ~40 (acc[7]+12 load+9 tap) -> __launch_bounds__(512,8)
// (VGPR<=64) without spill. No c-split -> no partial-sum exchange; one
// barrier; AO = 14 KB. Weight base readfirstlane'd -> s_load.
// ---------------------------------------------------------------------------
__global__ __launch_bounds__(512, 8) void conv_offmask_k(
    const float* __restrict__ x,
    const float* __restrict__ wom, const float* __restrict__ b_off,
    const float* __restrict__ b_mod,
    float* __restrict__ pyA, float* __restrict__ pxA, float* __restrict__ mA) {
    __shared__ float AO[28 * 128];         // 14 KB: o-quarter exchange

    int b    = blockIdx.x & 7;             // batch -> XCD (L2 locality)
    int hrow = blockIdx.x >> 3;            // 0..127 : pixel row
    int tid  = threadIdx.x;
    int t    = tid & 127;                  // pixel col
    int oq   = tid >> 7;                   // 0..3 : output quarter (wave-uniform)
    int qu   = __builtin_amdgcn_readfirstlane(oq);

    // stencil rows hrow-1..hrow+1 (clamped addr + block-uniform validity)
    int   yc0 = max(hrow - 1, 0);
    int   yc2 = min(hrow + 1, H_ - 1);
    float va0 = (hrow > 0) ? 1.0f : 0.0f;
    float va2 = (hrow < H_ - 1) ? 1.0f : 0.0f;

    // stencil cols t-1..t+1 from one dwordx4 at lc (edge lanes shifted)
    int  lc   = min(max(t - 1, 0), W_ - 4);
    bool t0   = (t == 0);
    bool t126 = (t == 126);
    bool t127 = (t == 127);

    const float* xb = x + b * C_ * HWSZ;

    float acc[7];
#pragma unroll
    for (int o = 0; o < 7; o++) acc[o] = 0.0f;

    for (int c = 0; c < C_; c++) {
        const float* xc = xb + c * HWSZ;
        f4u L0 = *(const f4u*)(xc + yc0  * W_ + lc);
        f4u L1 = *(const f4u*)(xc + hrow * W_ + lc);
        f4u L2 = *(const f4u*)(xc + yc2  * W_ + lc);

        // taps v[r*3+j] = x[hrow-1+r][t-1+j] (0 outside image)
        float v[9];
#define TAPS(R, LR, VM)                                                        \
        {                                                                      \
            float l0 = LR.x, l1 = LR.y, l2 = LR.z, l3 = LR.w;                  \
            v[(R)*3+0] = (t0 ? 0.0f : (t127 ? l2 : (t126 ? l1 : l0))) * (VM);  \
            v[(R)*3+1] = (t0 ? l0   : (t127 ? l3 : (t126 ? l2 : l1))) * (VM);  \
            v[(R)*3+2] = (t0 ? l1   : (t127 ? 0.0f : (t126 ? l3 : l2))) * (VM);\
        }
        TAPS(0, L0, va0)
        TAPS(1, L1, 1.0f)
        TAPS(2, L2, va2)
#undef TAPS

        const float* wq = wom + c * 252 + qu * 63;   // SGPR base -> s_load
#pragma unroll
        for (int o = 0; o < 7; o++) {
#pragma unroll
            for (int kk = 0; kk < 9; kk++)
                acc[o] += v[kk] * wq[o * 9 + kk];
        }
    }

    // quarter sums -> LDS (row 27 = zero-pad output, never read)
#pragma unroll
    for (int o = 0; o < 7; o++) AO[(qu * 7 + o) * 128 + t] = acc[o];
    __syncthreads();

    // epilogue: 128 threads, 1 pixel each, all 9 k's -> coords out
    if (tid < 128) {
        int p = hrow * W_ + t;
#pragma unroll
        for (int k = 0; k < 9; k++) {
            float dy = AO[(2 * k) * 128 + t]     + b_off[2 * k];
            float dx = AO[(2 * k + 1) * 128 + t] + b_off[2 * k + 1];
            float mm = AO[(18 + k) * 128 + t]    + b_mod[k];
            float mask = 2.0f / (1.0f + __expf(-mm));
            float py = dy + (float)hrow - 1.0f + (float)(k / 3);
            float px = dx + (float)t - 1.0f + (float)(k % 3);
            int idx = (b * 9 + k) * HWSZ + p;
            pyA[idx] = py;
            pxA[idx] = px;
            mA[idx] = mask;
        }
    }
}

// ---------------------------------------------------------------------------
// Kernel B (round-3 version, verbatim): bilinear sample + reduction GEMM,
// column-pair merged dwordx2 gathers. Measured 180us = TA roofline for this
// divergence pattern (~47 cy/wave-gather). Three LDS-staging attempts
// (r2/r6/r7) all lost to it on VALU/addressing overhead -- do not revisit.
// Occupancy can't rise: acc[64]/thread needs 64 VGPR alone (2 blocks/CU cap).
// ---------------------------------------------------------------------------
__global__ __launch_bounds__(512) void sample_gemm_k(
    const float* __restrict__ x,
    const float* __restrict__ pyA, const float* __restrict__ pxA,
    const float* __restrict__ mA, const float* __restrict__ wt,
    const float* __restrict__ bias, float* __restrict__ out) {
    __shared__ float red[O_ * 256];            // 64 KB

    int b     = blockIdx.x & 7;
    int strip = blockIdx.x >> 3;
    int tid   = threadIdx.x;
    int t     = tid & 255;
    int half  = tid >> 8;
    int c0    = __builtin_amdgcn_readfirstlane(half << 5);  // wave-uniform SGPR
    int p     = strip * 256 + t;

    float acc[O_];
#pragma unroll
    for (int o = 0; o < O_; o++) acc[o] = 0.0f;

    const float* xb = x + (b * C_ + c0) * HWSZ;

    for (int k = 0; k < 9; k++) {
        int idx = (b * 9 + k) * HWSZ + p;
        float py = pyA[idx];
        float px = pxA[idx];
        float m  = mA[idx];

        float y0f = floorf(py), x0f = floorf(px);
        float wy = py - y0f, wx = px - x0f;
        int y0 = (int)y0f, x0 = (int)x0f;
        int y1 = y0 + 1;
        float vy0 = (y0 >= 0 && y0 < H_) ? 1.0f : 0.0f;
        float vy1 = (y1 >= 0 && y1 < H_) ? 1.0f : 0.0f;
        float vx0 = (x0 >= 0 && x0 < W_) ? 1.0f : 0.0f;
        float vx1 = (x0 >= -1 && x0 < W_ - 1) ? 1.0f : 0.0f;
        int y0c = min(max(y0, 0), H_ - 1), y1c = min(max(y1, 0), H_ - 1);

        float w00 = (1.0f - wy) * (1.0f - wx) * vy0 * vx0 * m;
        float w01 = (1.0f - wy) * wx * vy0 * vx1 * m;
        float w10 = wy * (1.0f - wx) * vy1 * vx0 * m;
        float w11 = wy * wx * vy1 * vx1 * m;

        // column-pair merge: one 8B load per row covers both x-taps.
        int lc   = min(max(x0, 0), W_ - 2);    // 0..126, load [lc, lc+1]
        bool xlo = (x0 < 0);                   // v01 lives at f.x
        bool xhi = (x0 > W_ - 2);              // v00 lives at f.y
        float a00 = xhi ? 0.0f : (xlo ? w01 : w00);
        float a01 = xlo ? 0.0f : (xhi ? w00 : w01);
        float a10 = xhi ? 0.0f : (xlo ? w11 : w10);
        float a11 = xlo ? 0.0f : (xhi ? w10 : w11);

        int r0 = y0c * W_ + lc;
        int r1 = y1c * W_ + lc;

        const float* wp = wt + k * (C_ * O_) + c0 * O_;   // uniform -> s_load
        for (int c = 0; c < 32; c++) {
            const float* xc = xb + c * HWSZ;
            f2u f0 = *(const f2u*)(xc + r0);
            f2u f1 = *(const f2u*)(xc + r1);
            float s = a00 * f0.x + a01 * f0.y + a10 * f1.x + a11 * f1.y;
            const float* wpc = wp + c * O_;
#pragma unroll
            for (int o = 0; o < O_; o++) acc[o] += s * wpc[o];
        }
    }

    if (half) {
#pragma unroll
        for (int o = 0; o < O_; o++) red[o * 256 + t] = acc[o];  // stride-1
    }
    __syncthreads();
    if (!half) {
        int obase = b * O_ * HWSZ + p;
#pragma unroll
        for (int o = 0; o < O_; o++)
            out[obase + o * HWSZ] = acc[o] + red[o * 256 + t] + bias[o];
    }
}

// ---------------------------------------------------------------------------
extern "C" void kernel_launch(void* const* d_in, const int* in_sizes, int n_in,
                              void* d_out, int out_size, void* d_ws, size_t ws_size,
                              hipStream_t stream) {
    const float* x     = (const float*)d_in[0];
    const float* w_off = (const float*)d_in[1];
    const float* b_off = (const float*)d_in[2];
    const float* w_mod = (const float*)d_in[3];
    const float* b_mod = (const float*)d_in[4];
    const float* w     = (const float*)d_in[5];
    const float* bias  = (const float*)d_in[6];
    float* out = (float*)d_out;

    const int nCoord = B_ * K2_ * HWSZ;   // 1,179,648
    float* pyA = (float*)d_ws;
    float* pxA = pyA + nCoord;
    float* mA  = pxA + nCoord;
    float* wt  = mA + nCoord;             // 36,864 floats
    float* wom = wt + K2_ * C_ * O_;      // 16,128 floats (C*28*9)

    const int nPrep = K2_ * C_ * O_ + C_ * 252;   // 52,992
    hipLaunchKernelGGL(prep_weights_k, dim3((nPrep + 255) / 256), dim3(256),
                       0, stream, w, w_off, w_mod, wt, wom);
    hipLaunchKernelGGL(conv_offmask_k, dim3(1024), dim3(512), 0, stream,
                       x, wom, b_off, b_mod, pyA, pxA, mA);
    hipLaunchKernelGGL(sample_gemm_k, dim3(512), dim3(512), 0, stream,
                       x, pyA, pxA, mA, wt, bias, out);
}